// Round 6
// baseline (1776.346 us; speedup 1.0000x reference)
//
#include <hip/hip_runtime.h>
#include <hip/hip_bf16.h>

#define BT_ 8192   // B*T
#define D_  512
#define V_  8192
#define NT2 32     // V / 256 col-tiles

// ---- INSTRUMENTATION (this round only): force kernels into rocprof top-5 ----
#define GREPS 8    // gemm8 internal K-loop repetitions (last rep is the real one)
#define RF_REPS 5  // row_finish launch repetitions (idempotent)

// d_out float offsets (outputs concatenated in return order)
#define OFF_Q      0
#define OFF_TOK    4194304
#define OFF_LOSS   4202496
#define OFF_SOFT   4202497
#define OFF_LOGITS 71311361
#define STAGE_F    4202500   // bf16 staging scratch inside soft region (16B-aligned)

#define TAU  0.02f

typedef __attribute__((ext_vector_type(8))) short bf16x8;
typedef __attribute__((ext_vector_type(4))) float f32x4;
typedef __attribute__((ext_vector_type(4))) unsigned short u16x4;

__device__ __forceinline__ unsigned short bf16rne(float f) {
  unsigned int u = __float_as_uint(f);
  return (unsigned short)((u + 0x7fffu + ((u >> 16) & 1u)) >> 16);
}

// ---------------- pass 0: fp32 -> bf16 for X and W (block-uniform source) ----------------
__global__ __launch_bounds__(256) void to_bf16_k(const float4* __restrict__ x,
                                                 const float4* __restrict__ w,
                                                 u16x4* __restrict__ xa,
                                                 u16x4* __restrict__ wb) {
  const int n4 = (BT_ * D_) / 4;
  const int half = gridDim.x >> 1;
  const bool isw = blockIdx.x >= half;
  const float4* __restrict__ s = isw ? w : x;
  u16x4* __restrict__ d = isw ? wb : xa;
  const int b0 = isw ? blockIdx.x - half : blockIdx.x;
  for (int i = b0 * 256 + threadIdx.x; i < n4; i += half * 256) {
    const float4 v = s[i];
    u16x4 o;
    o[0] = bf16rne(v.x); o[1] = bf16rne(v.y);
    o[2] = bf16rne(v.z); o[3] = bf16rne(v.w);
    d[i] = o;
  }
}

// ---------------- pass 1: 256x256 8-phase bf16 MFMA GEMM + per-tile row stats ----------------
__device__ __forceinline__ void gload_lds16(const void* g, void* l) {
  __builtin_amdgcn_global_load_lds((const __attribute__((address_space(1))) void*)g,
                                   (__attribute__((address_space(3))) void*)l,
                                   16, 0, 0);
}

// raw barrier + compiler memory fence (no vmcnt/lgkm drain)
__device__ __forceinline__ void barf() {
  __builtin_amdgcn_s_barrier();
  asm volatile("" ::: "memory");
}
__device__ __forceinline__ void vmcnt2() { asm volatile("s_waitcnt vmcnt(2)" ::: "memory"); }
__device__ __forceinline__ void vmcnt0() { asm volatile("s_waitcnt vmcnt(0)" ::: "memory"); }

// stage one half-tile (16 KB = 2 issues x 512 lanes x 16B) of K-tile `ktile`.
// LDS dest linear; global source inverse-swizzled (T2 both-sides rule).
// Swizzle: 3-bit XOR, addr ^= ((row&7)<<4).
__device__ __forceinline__ void stage_unit(const char* __restrict__ tb, char* ldsRegion,
                                           int ktile, int half, int wid, int lane) {
#pragma unroll
  for (int issue = 0; issue < 2; ++issue) {
    const int d = half * 16384 + issue * 8192 + wid * 1024 + lane * 16;
    const int l = d ^ (((d >> 7) & 7) << 4);
    gload_lds16(tb + (size_t)(l >> 7) * 1024 + ktile * 128 + (l & 127),
                ldsRegion + half * 16384 + issue * 8192 + wid * 1024);
  }
}

// swizzled fragment read: logical (row R, k-bytes ks*64 + 16*g)
__device__ __forceinline__ bf16x8 rdfrag(const char* base, int R, int ks, int g) {
  return *(const bf16x8*)(base + R * 128 + ((ks * 64 + 16 * g) ^ ((R & 7) << 4)));
}

__device__ __forceinline__ void kgroup(int t, int smode, char* lds,
                                       const char* __restrict__ Ab,
                                       const char* __restrict__ Bb,
                                       int wr, int wc, int lane, int wid,
                                       f32x4 (&acc)[8][4]) {
  char* aL = lds + (t & 1) * 32768;
  char* bL = lds + 65536 + (t & 1) * 32768;
  char* aS = lds + ((t & 1) ^ 1) * 32768;
  char* bS = lds + 65536 + ((t & 1) ^ 1) * 32768;
  const int cg = lane & 15, g = lane >> 4;
  bf16x8 a[4][2], b0[2][2], b1[2][2];

  // ---- phase 1: read A01 + B01 of t; stage (t+1).A-half1
#pragma unroll
  for (int m = 0; m < 4; ++m)
#pragma unroll
    for (int ks = 0; ks < 2; ++ks)
      a[m][ks] = rdfrag(aL, wr * 128 + m * 16 + cg, ks, g);
#pragma unroll
  for (int n = 0; n < 2; ++n)
#pragma unroll
    for (int ks = 0; ks < 2; ++ks)
      b0[n][ks] = rdfrag(bL, wc * 64 + n * 16 + cg, ks, g);
  if (smode >= 1) stage_unit(Ab, aS, t + 1, 1, wid, lane);
  barf();
  __builtin_amdgcn_s_setprio(1);
#pragma unroll
  for (int m = 0; m < 4; ++m)
#pragma unroll
    for (int n = 0; n < 2; ++n)
#pragma unroll
      for (int ks = 0; ks < 2; ++ks)
        acc[m][n] = __builtin_amdgcn_mfma_f32_16x16x32_bf16(a[m][ks], b0[n][ks], acc[m][n], 0, 0, 0);
  __builtin_amdgcn_s_setprio(0);
  barf();

  // ---- phase 2: read B23 of t; stage (t+1).B-half0
#pragma unroll
  for (int n = 0; n < 2; ++n)
#pragma unroll
    for (int ks = 0; ks < 2; ++ks)
      b1[n][ks] = rdfrag(bL, wc * 64 + (n + 2) * 16 + cg, ks, g);
  if (smode >= 1) stage_unit(Bb, bS, t + 1, 0, wid, lane);
  barf();
  __builtin_amdgcn_s_setprio(1);
#pragma unroll
  for (int m = 0; m < 4; ++m)
#pragma unroll
    for (int n = 0; n < 2; ++n)
#pragma unroll
      for (int ks = 0; ks < 2; ++ks)
        acc[m][n + 2] = __builtin_amdgcn_mfma_f32_16x16x32_bf16(a[m][ks], b1[n][ks], acc[m][n + 2], 0, 0, 0);
  __builtin_amdgcn_s_setprio(0);
  barf();

  // ---- phase 3: read A23 of t (overwrite a); stage (t+1).B-half1
#pragma unroll
  for (int m = 0; m < 4; ++m)
#pragma unroll
    for (int ks = 0; ks < 2; ++ks)
      a[m][ks] = rdfrag(aL, wr * 128 + (m + 4) * 16 + cg, ks, g);
  if (smode >= 1) stage_unit(Bb, bS, t + 1, 1, wid, lane);
  barf();
  __builtin_amdgcn_s_setprio(1);
#pragma unroll
  for (int m = 0; m < 4; ++m)
#pragma unroll
    for (int n = 0; n < 2; ++n)
#pragma unroll
      for (int ks = 0; ks < 2; ++ks)
        acc[m + 4][n + 2] = __builtin_amdgcn_mfma_f32_16x16x32_bf16(a[m][ks], b1[n][ks], acc[m + 4][n + 2], 0, 0, 0);
  __builtin_amdgcn_s_setprio(0);
  barf();

  // ---- phase 4: MFMA A23 x B01 (regs only); stage (t+2).A-half0 into read-parity buf
  if (smode == 2) stage_unit(Ab, aL, t + 2, 0, wid, lane);  // safe: all t-reads retired by ph3
  barf();
  __builtin_amdgcn_s_setprio(1);
#pragma unroll
  for (int m = 0; m < 4; ++m)
#pragma unroll
    for (int n = 0; n < 2; ++n)
#pragma unroll
      for (int ks = 0; ks < 2; ++ks)
        acc[m + 4][n] = __builtin_amdgcn_mfma_f32_16x16x32_bf16(a[m][ks], b0[n][ks], acc[m + 4][n], 0, 0, 0);
  __builtin_amdgcn_s_setprio(0);
  if (smode == 2) vmcnt2();        // ledger: only (t+2).A0 (2 loads) may stay in flight
  else if (smode == 1) vmcnt0();   // tail: tile7 fully staged, nothing younger
  barf();
}

__global__ __launch_bounds__(512, 2) void gemm8(const unsigned short* __restrict__ A,
                                                const unsigned short* __restrict__ B,
                                                const float* __restrict__ bias,
                                                float* __restrict__ C,
                                                float* __restrict__ pmaxT,
                                                float* __restrict__ psumT) {
  __shared__ char lds[131072];  // A dbuf 64K | B dbuf 64K
  const int tid  = threadIdx.x;
  const int lane = tid & 63;
  const int wid  = tid >> 6;           // 8 waves: 2M x 4N
  const int wr   = wid >> 2, wc = wid & 3;

  // bijective XCD chunking over the 32x32 block grid (8x16 blocks per XCD)
  const int bid = blockIdx.x;
  const int xcd = bid & 7;
  const int s   = bid >> 3;
  const int by  = (xcd >> 1) * 8 + (s >> 4);
  const int bx  = (xcd & 1) * 16 + (s & 15);
  const int row0 = by * 256, col0 = bx * 256;

  const char* Ab = (const char*)A + (size_t)row0 * 1024;
  const char* Bb = (const char*)B + (size_t)col0 * 1024;

  f32x4 acc[8][4];

  // INSTRUMENTATION: repeat the full {zero-acc, prologue, K-loop} GREPS times.
  // Only the final rep's acc survives into the epilogue -> outputs identical.
  // Per-rep LDS overwrite is safe: all ds_reads of the previous rep are
  // register-retired before its final barrier.
#pragma unroll 1
  for (int rep = 0; rep < GREPS; ++rep) {
#pragma unroll
    for (int m = 0; m < 8; ++m)
#pragma unroll
      for (int n = 0; n < 4; ++n)
#pragma unroll
        for (int j = 0; j < 4; ++j)
          acc[m][n][j] = 0.f;

    // prologue: stage tile0 fully + tile1.A-half0; wait tile0 (2 younger in flight)
    stage_unit(Ab, lds, 0, 0, wid, lane);
    stage_unit(Ab, lds, 0, 1, wid, lane);
    stage_unit(Bb, lds + 65536, 0, 0, wid, lane);
    stage_unit(Bb, lds + 65536, 0, 1, wid, lane);
    stage_unit(Ab, lds + 32768, 1, 0, wid, lane);
    vmcnt2();
    barf();

    for (int t = 0; t < 6; ++t)
      kgroup(t, 2, lds, Ab, Bb, wr, wc, lane, wid, acc);
    kgroup(6, 1, lds, Ab, Bb, wr, wc, lane, wid, acc);
    kgroup(7, 0, lds, Ab, Bb, wr, wc, lane, wid, acc);
  }

  // ---- epilogue: C-write + per-row {max, sumexp} over this block's 256 cols ----
  float* pmS = (float*)lds;           // [4][256]
  float* psS = (float*)lds + 1024;    // [4][256]
  const int cg = lane & 15, g = lane >> 4;

  float bv[4];
#pragma unroll
  for (int n = 0; n < 4; ++n) bv[n] = bias[col0 + wc * 64 + n * 16 + cg];

#pragma unroll
  for (int m = 0; m < 8; ++m) {
#pragma unroll
    for (int rr = 0; rr < 4; ++rr) {
      const int R = wr * 128 + m * 16 + 4 * g + rr;
      const size_t rowg = row0 + R;
      float vmx = -1e30f, vsm = 0.f;
#pragma unroll
      for (int n = 0; n < 4; ++n) {
        const float v = acc[m][n][rr] + bv[n];
        C[rowg * V_ + col0 + wc * 64 + n * 16 + cg] = v;
        vmx = fmaxf(vmx, v);
        vsm += __expf(v);
      }
#pragma unroll
      for (int o = 1; o < 16; o <<= 1) {
        vmx = fmaxf(vmx, __shfl_xor(vmx, o));
        vsm += __shfl_xor(vsm, o);
      }
      if (cg == 0) { pmS[wc * 256 + R] = vmx; psS[wc * 256 + R] = vsm; }
    }
  }
  __syncthreads();
  if (tid < 256) {
    float mx = fmaxf(fmaxf(pmS[tid], pmS[256 + tid]), fmaxf(pmS[512 + tid], pmS[768 + tid]));
    float sm = psS[tid] + psS[256 + tid] + psS[512 + tid] + psS[768 + tid];
    pmaxT[(size_t)bx * BT_ + row0 + tid] = mx;
    psumT[(size_t)bx * BT_ + row0 + tid] = sm;
  }
}

// ---- pass 2: per-row reduce partials, exact-fp32 argmax rescue, softmax sweep ----
__global__ __launch_bounds__(256) void row_finish(const float* __restrict__ logits,
                                                  const float* __restrict__ pmaxT,
                                                  const float* __restrict__ psumT,
                                                  const float* __restrict__ xf,
                                                  const float* __restrict__ wf,
                                                  const float* __restrict__ bias,
                                                  float* __restrict__ tokf,
                                                  float* __restrict__ soft) {
  const int row  = blockIdx.x;
  const int tid  = threadIdx.x;
  const int lane = tid & 63;
  const int wv   = tid >> 6;

  const int tl = lane & 31;                          // tile index (dup in high lanes)
  const float pm = pmaxT[(size_t)tl * BT_ + row];
  const float ps = psumT[(size_t)tl * BT_ + row];
  float m = pm, s = ps;
#pragma unroll
  for (int o = 1; o < 32; o <<= 1) {
    m = fmaxf(m, __shfl_xor(m, o));
    s += __shfl_xor(s, o);
  }
  const float si = 1.0f / s;

  const float* L = logits + (size_t)row * V_;
  float*       S = soft   + (size_t)row * V_;
  const float4* L4 = (const float4*)(L + 3);  // region base ==1 mod 4 -> +3 is 16B-aligned
  float4*       S4 = (float4*)(S + 3);

  if (wv == 0) {
    // ---- argmax rescue on wave 0 ----
    const float thr = m - TAU;
    unsigned long long tmask = __ballot(pm >= thr) & 0xFFFFFFFFull;
    float bestv = -1e30f;
    int   besti = 0x7fffffff;
    const float4* xr4 = (const float4*)(xf + (size_t)row * D_);
    while (tmask) {
      const int t = __ffsll(tmask) - 1;
      tmask &= tmask - 1;
      const float* Lr = L + t * 256;
#pragma unroll
      for (int kq = 0; kq < 4; ++kq) {
        const float lv = Lr[kq * 64 + lane];
        unsigned long long c = __ballot(lv >= thr);
        while (c) {
          const int j = __ffsll(c) - 1;
          c &= c - 1;
          const int col = t * 256 + kq * 64 + j;
          const float4* wr4 = (const float4*)(wf + (size_t)col * D_);
          float p = 0.f;
#pragma unroll
          for (int q = 0; q < 2; ++q) {
            const float4 av = xr4[lane + 64 * q];
            const float4 bvv = wr4[lane + 64 * q];
            p += av.x * bvv.x + av.y * bvv.y + av.z * bvv.z + av.w * bvv.w;
          }
#pragma unroll
          for (int o = 1; o < 64; o <<= 1) p += __shfl_xor(p, o);
          const float tot = p + bias[col];
          if (tot > bestv || (tot == bestv && col < besti)) { bestv = tot; besti = col; }
        }
      }
    }
    if (lane == 0) tokf[row] = (float)besti;
    // wave0's small static sweep share + head/tail
    if (lane < 3)  S[lane] = __expf(L[lane]) * si;
    if (lane == 3) S[8191] = __expf(L[8191]) * si;
#pragma unroll
    for (int k = 0; k < 2; ++k) {
      const int i = 1920 + k * 64 + lane;
      if (i < 2047) {
        const float4 v = L4[i];
        float4 o;
        o.x = __expf(v.x) * si; o.y = __expf(v.y) * si;
        o.z = __expf(v.z) * si; o.w = __expf(v.w) * si;
        S4[i] = o;
      }
    }
  } else {
    // waves 1-3: bulk sweep [0, 1920) immediately, no barrier
    const int t = tid - 64;  // 0..191
#pragma unroll
    for (int k = 0; k < 10; ++k) {
      const int i = k * 192 + t;
      const float4 v = L4[i];
      float4 o;
      o.x = __expf(v.x) * si; o.y = __expf(v.y) * si;
      o.z = __expf(v.z) * si; o.w = __expf(v.w) * si;
      S4[i] = o;
    }
  }
}

// ---------------- pass 3: quantized gather + commitment loss ----------------
__global__ __launch_bounds__(256) void finalize_k(const float* __restrict__ tokf,
                                                  const float* __restrict__ cb,
                                                  const float* __restrict__ xf,
                                                  float* __restrict__ q,
                                                  float* __restrict__ loss) {
  const int row  = blockIdx.x * 4 + (threadIdx.x >> 6);
  const int lane = threadIdx.x & 63;
  const int idx  = (int)tokf[row];
  const float4* cr = (const float4*)(cb + (size_t)idx * D_);
  const float4* xr = (const float4*)(xf + (size_t)row * D_);
  float4* qr = (float4*)(q + (size_t)row * D_);
  float ls = 0.f;
#pragma unroll
  for (int j = 0; j < 2; ++j) {
    const int c = lane + j * 64;
    const float4 cv = cr[c];
    const float4 xv = xr[c];
    qr[c] = cv;
    const float dx = cv.x - xv.x, dy = cv.y - xv.y, dz = cv.z - xv.z, dw = cv.w - xv.w;
    ls += dx * dx + dy * dy + dz * dz + dw * dw;
  }
#pragma unroll
  for (int o = 32; o; o >>= 1) ls += __shfl_xor(ls, o);
  if (lane == 0) atomicAdd(loss, ls * (1.0f / 4194304.0f));
}

extern "C" void kernel_launch(void* const* d_in, const int* in_sizes, int n_in,
                              void* d_out, int out_size, void* d_ws, size_t ws_size,
                              hipStream_t stream) {
  const float* x  = (const float*)d_in[0];  // inputs   [8192][512]
  const float* cb = (const float*)d_in[1];  // codebook [8192][512]
  const float* wl = (const float*)d_in[2];  // W_logits [8192][512]
  const float* bl = (const float*)d_in[3];  // b_logits [8192]
  float* out = (float*)d_out;

  float* qout   = out + OFF_Q;
  float* tokf   = out + OFF_TOK;
  float* loss   = out + OFF_LOSS;
  float* soft   = out + OFF_SOFT;
  float* logits = out + OFF_LOGITS;

  // scratch carved from output regions (each rewritten later in the pipeline):
  unsigned short* Abf = (unsigned short*)(out + STAGE_F);  // in soft region
  unsigned short* Wbf = Abf + (size_t)BT_ * D_;
  float* pmaxT = qout;            // [32][8192] in quantized region (finalize overwrites last)
  float* psumT = qout + 262144;   // [32][8192]

  hipMemsetAsync(loss, 0, 4, stream);

  to_bf16_k<<<2048, 256, 0, stream>>>((const float4*)x, (const float4*)wl,
                                      (u16x4*)Abf, (u16x4*)Wbf);
  gemm8<<<1024, 512, 0, stream>>>(Abf, Wbf, bl, logits, pmaxT, psumT);
  // INSTRUMENTATION: RF_REPS idempotent launches -> per-dispatch dur in rocprof
  for (int r = 0; r < RF_REPS; ++r)
    row_finish<<<8192, 256, 0, stream>>>(logits, pmaxT, psumT, x, wl, bl, tokf, soft);
  finalize_k<<<2048, 256, 0, stream>>>(tokf, cb, x, qout, loss);
}

// Round 7
// 382.668 us; speedup vs baseline: 4.6420x; 4.6420x over previous
//
#include <hip/hip_runtime.h>
#include <hip/hip_bf16.h>

#define BT_ 8192   // B*T
#define D_  512
#define V_  8192
#define NT2 32     // V / 256 col-tiles

// d_out float offsets (outputs concatenated in return order)
#define OFF_Q      0
#define OFF_TOK    4194304
#define OFF_LOSS   4202496
#define OFF_SOFT   4202497
#define OFF_LOGITS 71311361
#define STAGE_F    4202500   // bf16 staging scratch inside soft region (16B-aligned)

#define TAU  0.02f

typedef __attribute__((ext_vector_type(8))) short bf16x8;
typedef __attribute__((ext_vector_type(4))) float f32x4;
typedef __attribute__((ext_vector_type(4))) unsigned short u16x4;

__device__ __forceinline__ unsigned short bf16rne(float f) {
  unsigned int u = __float_as_uint(f);
  return (unsigned short)((u + 0x7fffu + ((u >> 16) & 1u)) >> 16);
}

// ---------------- pass 0: fp32 -> bf16 for X and W (block-uniform source) ----------------
__global__ __launch_bounds__(256) void to_bf16_k(const f32x4* __restrict__ x,
                                                 const f32x4* __restrict__ w,
                                                 u16x4* __restrict__ xa,
                                                 u16x4* __restrict__ wb) {
  const int n4 = (BT_ * D_) / 4;
  const int half = gridDim.x >> 1;
  const bool isw = blockIdx.x >= half;
  const f32x4* __restrict__ s = isw ? w : x;
  u16x4* __restrict__ d = isw ? wb : xa;
  const int b0 = isw ? blockIdx.x - half : blockIdx.x;
  for (int i = b0 * 256 + threadIdx.x; i < n4; i += half * 256) {
    const f32x4 v = __builtin_nontemporal_load(s + i);  // read-once stream
    u16x4 o;
    o[0] = bf16rne(v[0]); o[1] = bf16rne(v[1]);
    o[2] = bf16rne(v[2]); o[3] = bf16rne(v[3]);
    d[i] = o;   // cached: gemm re-reads soon
  }
}

// ---------------- pass 1: 256x256 8-phase bf16 MFMA GEMM + fused stats epilogue ----------------
__device__ __forceinline__ void gload_lds16(const void* g, void* l) {
  __builtin_amdgcn_global_load_lds((const __attribute__((address_space(1))) void*)g,
                                   (__attribute__((address_space(3))) void*)l,
                                   16, 0, 0);
}

// raw barrier + compiler memory fence (no vmcnt/lgkm drain)
__device__ __forceinline__ void barf() {
  __builtin_amdgcn_s_barrier();
  asm volatile("" ::: "memory");
}
__device__ __forceinline__ void vmcnt2() { asm volatile("s_waitcnt vmcnt(2)" ::: "memory"); }
__device__ __forceinline__ void vmcnt0() { asm volatile("s_waitcnt vmcnt(0)" ::: "memory"); }

// stage one half-tile (16 KB = 2 issues x 512 lanes x 16B) of K-tile `ktile`.
// LDS dest linear; global source inverse-swizzled (T2 both-sides rule).
// Swizzle: 3-bit XOR, addr ^= ((row&7)<<4).
__device__ __forceinline__ void stage_unit(const char* __restrict__ tb, char* ldsRegion,
                                           int ktile, int half, int wid, int lane) {
#pragma unroll
  for (int issue = 0; issue < 2; ++issue) {
    const int d = half * 16384 + issue * 8192 + wid * 1024 + lane * 16;
    const int l = d ^ (((d >> 7) & 7) << 4);
    gload_lds16(tb + (size_t)(l >> 7) * 1024 + ktile * 128 + (l & 127),
                ldsRegion + half * 16384 + issue * 8192 + wid * 1024);
  }
}

// swizzled fragment read: logical (row R, k-bytes ks*64 + 16*g)
__device__ __forceinline__ bf16x8 rdfrag(const char* base, int R, int ks, int g) {
  return *(const bf16x8*)(base + R * 128 + ((ks * 64 + 16 * g) ^ ((R & 7) << 4)));
}

__device__ __forceinline__ void kgroup(int t, int smode, char* lds,
                                       const char* __restrict__ Ab,
                                       const char* __restrict__ Bb,
                                       int wr, int wc, int lane, int wid,
                                       f32x4 (&acc)[8][4]) {
  char* aL = lds + (t & 1) * 32768;
  char* bL = lds + 65536 + (t & 1) * 32768;
  char* aS = lds + ((t & 1) ^ 1) * 32768;
  char* bS = lds + 65536 + ((t & 1) ^ 1) * 32768;
  const int cg = lane & 15, g = lane >> 4;
  bf16x8 a[4][2], b0[2][2], b1[2][2];

  // ---- phase 1: read A01 + B01 of t; stage (t+1).A-half1
#pragma unroll
  for (int m = 0; m < 4; ++m)
#pragma unroll
    for (int ks = 0; ks < 2; ++ks)
      a[m][ks] = rdfrag(aL, wr * 128 + m * 16 + cg, ks, g);
#pragma unroll
  for (int n = 0; n < 2; ++n)
#pragma unroll
    for (int ks = 0; ks < 2; ++ks)
      b0[n][ks] = rdfrag(bL, wc * 64 + n * 16 + cg, ks, g);
  if (smode >= 1) stage_unit(Ab, aS, t + 1, 1, wid, lane);
  barf();
  __builtin_amdgcn_s_setprio(1);
#pragma unroll
  for (int m = 0; m < 4; ++m)
#pragma unroll
    for (int n = 0; n < 2; ++n)
#pragma unroll
      for (int ks = 0; ks < 2; ++ks)
        acc[m][n] = __builtin_amdgcn_mfma_f32_16x16x32_bf16(a[m][ks], b0[n][ks], acc[m][n], 0, 0, 0);
  __builtin_amdgcn_s_setprio(0);
  barf();

  // ---- phase 2: read B23 of t; stage (t+1).B-half0
#pragma unroll
  for (int n = 0; n < 2; ++n)
#pragma unroll
    for (int ks = 0; ks < 2; ++ks)
      b1[n][ks] = rdfrag(bL, wc * 64 + (n + 2) * 16 + cg, ks, g);
  if (smode >= 1) stage_unit(Bb, bS, t + 1, 0, wid, lane);
  barf();
  __builtin_amdgcn_s_setprio(1);
#pragma unroll
  for (int m = 0; m < 4; ++m)
#pragma unroll
    for (int n = 0; n < 2; ++n)
#pragma unroll
      for (int ks = 0; ks < 2; ++ks)
        acc[m][n + 2] = __builtin_amdgcn_mfma_f32_16x16x32_bf16(a[m][ks], b1[n][ks], acc[m][n + 2], 0, 0, 0);
  __builtin_amdgcn_s_setprio(0);
  barf();

  // ---- phase 3: read A23 of t (overwrite a); stage (t+1).B-half1
#pragma unroll
  for (int m = 0; m < 4; ++m)
#pragma unroll
    for (int ks = 0; ks < 2; ++ks)
      a[m][ks] = rdfrag(aL, wr * 128 + (m + 4) * 16 + cg, ks, g);
  if (smode >= 1) stage_unit(Bb, bS, t + 1, 1, wid, lane);
  barf();
  __builtin_amdgcn_s_setprio(1);
#pragma unroll
  for (int m = 0; m < 4; ++m)
#pragma unroll
    for (int n = 0; n < 2; ++n)
#pragma unroll
      for (int ks = 0; ks < 2; ++ks)
        acc[m + 4][n + 2] = __builtin_amdgcn_mfma_f32_16x16x32_bf16(a[m][ks], b1[n][ks], acc[m + 4][n + 2], 0, 0, 0);
  __builtin_amdgcn_s_setprio(0);
  barf();

  // ---- phase 4: MFMA A23 x B01 (regs only); stage (t+2).A-half0 into read-parity buf
  if (smode == 2) stage_unit(Ab, aL, t + 2, 0, wid, lane);  // safe: all t-reads retired by ph3
  barf();
  __builtin_amdgcn_s_setprio(1);
#pragma unroll
  for (int m = 0; m < 4; ++m)
#pragma unroll
    for (int n = 0; n < 2; ++n)
#pragma unroll
      for (int ks = 0; ks < 2; ++ks)
        acc[m + 4][n] = __builtin_amdgcn_mfma_f32_16x16x32_bf16(a[m][ks], b0[n][ks], acc[m + 4][n], 0, 0, 0);
  __builtin_amdgcn_s_setprio(0);
  if (smode == 2) vmcnt2();        // ledger: only (t+2).A0 (2 loads) may stay in flight
  else if (smode == 1) vmcnt0();   // tail: tile7 fully staged, nothing younger
  barf();
}

__global__ __launch_bounds__(512) void gemm8(const unsigned short* __restrict__ A,
                                             const unsigned short* __restrict__ B,
                                             const float* __restrict__ bias,
                                             float* __restrict__ C,
                                             float* __restrict__ pmaxT,
                                             float* __restrict__ psumT) {
  __shared__ char lds[131072];  // A dbuf 64K | B dbuf 64K ; reused as C retile [128][256] f32
  const int tid  = threadIdx.x;
  const int lane = tid & 63;
  const int wid  = tid >> 6;           // 8 waves: 2M x 4N
  const int wr   = wid >> 2, wc = wid & 3;

  // bijective XCD chunking over the 32x32 block grid (8x16 blocks per XCD)
  const int bid = blockIdx.x;
  const int xcd = bid & 7;
  const int s   = bid >> 3;
  const int by  = (xcd >> 1) * 8 + (s >> 4);
  const int bx  = (xcd & 1) * 16 + (s & 15);
  const int row0 = by * 256, col0 = bx * 256;

  const char* Ab = (const char*)A + (size_t)row0 * 1024;
  const char* Bb = (const char*)B + (size_t)col0 * 1024;

  f32x4 acc[8][4] = {};

  // prologue: stage tile0 fully + tile1.A-half0; wait tile0 (2 younger in flight)
  stage_unit(Ab, lds, 0, 0, wid, lane);
  stage_unit(Ab, lds, 0, 1, wid, lane);
  stage_unit(Bb, lds + 65536, 0, 0, wid, lane);
  stage_unit(Bb, lds + 65536, 0, 1, wid, lane);
  stage_unit(Ab, lds + 32768, 1, 0, wid, lane);
  vmcnt2();
  barf();

  for (int t = 0; t < 6; ++t)
    kgroup(t, 2, lds, Ab, Bb, wr, wc, lane, wid, acc);
  kgroup(6, 1, lds, Ab, Bb, wr, wc, lane, wid, acc);
  kgroup(7, 0, lds, Ab, Bb, wr, wc, lane, wid, acc);

  // ---- epilogue: LDS retile -> coalesced nt row stores + per-row {max,sumexp} ----
  // LDS rows rotated by -3 cols so the (base%4==1) global misalignment maps to
  // aligned LDS f32x4 reads: lds word (c+253)&255 holds col c.
  const int cg = lane & 15, g = lane >> 4;
  float bv[4];
#pragma unroll
  for (int n = 0; n < 4; ++n) bv[n] = bias[col0 + wc * 64 + n * 16 + cg];

  float* cl = (float*)lds;
  __syncthreads();
#pragma unroll
  for (int h = 0; h < 2; ++h) {
    if (wr == h) {
#pragma unroll
      for (int m = 0; m < 8; ++m)
#pragma unroll
        for (int n = 0; n < 4; ++n) {
          const int cw = ((wc * 64 + n * 16 + cg) + 253) & 255;
#pragma unroll
          for (int rr = 0; rr < 4; ++rr) {
            const int R = m * 16 + 4 * g + rr;   // local row 0..127
            cl[R * 256 + cw] = acc[m][n][rr] + bv[n];
          }
        }
    }
    __syncthreads();
    // each wave streams 16 rows: aligned f32x4 LDS read -> 1KB-contiguous nt store
#pragma unroll
    for (int k = 0; k < 16; ++k) {
      const int r = wid * 16 + k;
      const f32x4 v = *(const f32x4*)((char*)cl + r * 1024 + lane * 16);
      float vmx = fmaxf(fmaxf(v[0], v[1]), fmaxf(v[2], v[3]));
      float vsm = __expf(v[0]) + __expf(v[1]) + __expf(v[2]) + __expf(v[3]);
#pragma unroll
      for (int o = 1; o < 64; o <<= 1) {
        vmx = fmaxf(vmx, __shfl_xor(vmx, o));
        vsm += __shfl_xor(vsm, o);
      }
      const int grow = row0 + h * 128 + r;
      float* Crow = C + (size_t)grow * V_ + col0;
      if (lane < 63) {
        __builtin_nontemporal_store(v, (f32x4*)(Crow + 3) + lane);  // cols 3+4l..+3
      } else {
        // lane63's f32x4 = cols {255, 0, 1, 2} (row rotation wrap)
        __builtin_nontemporal_store(v[0], Crow + 255);
        __builtin_nontemporal_store(v[1], Crow + 0);
        __builtin_nontemporal_store(v[2], Crow + 1);
        __builtin_nontemporal_store(v[3], Crow + 2);
      }
      if (lane == 0) {
        pmaxT[(size_t)bx * BT_ + grow] = vmx;   // cached: row_finish reads next
        psumT[(size_t)bx * BT_ + grow] = vsm;
      }
    }
    __syncthreads();
  }
}

// ---- pass 2: per-row reduce partials, exact-fp32 argmax rescue, softmax sweep ----
__global__ __launch_bounds__(256) void row_finish(const float* __restrict__ logits,
                                                  const float* __restrict__ pmaxT,
                                                  const float* __restrict__ psumT,
                                                  const float* __restrict__ xf,
                                                  const float* __restrict__ wf,
                                                  const float* __restrict__ bias,
                                                  float* __restrict__ tokf,
                                                  float* __restrict__ soft) {
  const int row  = blockIdx.x;
  const int tid  = threadIdx.x;
  const int lane = tid & 63;
  const int wv   = tid >> 6;

  const int tl = lane & 31;                          // tile index (dup in high lanes)
  const float pm = pmaxT[(size_t)tl * BT_ + row];
  const float ps = psumT[(size_t)tl * BT_ + row];
  float m = pm, s = ps;
#pragma unroll
  for (int o = 1; o < 32; o <<= 1) {
    m = fmaxf(m, __shfl_xor(m, o));
    s += __shfl_xor(s, o);
  }
  const float si = 1.0f / s;

  const float* L = logits + (size_t)row * V_;
  float*       S = soft   + (size_t)row * V_;
  const f32x4* L4 = (const f32x4*)(L + 3);  // region base ==1 mod 4 -> +3 is 16B-aligned
  f32x4*       S4 = (f32x4*)(S + 3);

  if (wv == 0) {
    // ---- argmax rescue on wave 0 ----
    const float thr = m - TAU;
    unsigned long long tmask = __ballot(pm >= thr) & 0xFFFFFFFFull;
    float bestv = -1e30f;
    int   besti = 0x7fffffff;
    const float4* xr4 = (const float4*)(xf + (size_t)row * D_);
    while (tmask) {
      const int t = __ffsll(tmask) - 1;
      tmask &= tmask - 1;
      const float* Lr = L + t * 256;
#pragma unroll
      for (int kq = 0; kq < 4; ++kq) {
        const float lv = Lr[kq * 64 + lane];
        unsigned long long c = __ballot(lv >= thr);
        while (c) {
          const int j = __ffsll(c) - 1;
          c &= c - 1;
          const int col = t * 256 + kq * 64 + j;
          const float4* wr4 = (const float4*)(wf + (size_t)col * D_);
          float p = 0.f;
#pragma unroll
          for (int q = 0; q < 2; ++q) {
            const float4 av = xr4[lane + 64 * q];
            const float4 bvv = wr4[lane + 64 * q];
            p += av.x * bvv.x + av.y * bvv.y + av.z * bvv.z + av.w * bvv.w;
          }
#pragma unroll
          for (int o = 1; o < 64; o <<= 1) p += __shfl_xor(p, o);
          const float tot = p + bias[col];
          if (tot > bestv || (tot == bestv && col < besti)) { bestv = tot; besti = col; }
        }
      }
    }
    if (lane == 0) tokf[row] = (float)besti;
    // wave0's small static sweep share + head/tail
    if (lane < 3)  S[lane] = __expf(L[lane]) * si;
    if (lane == 3) S[8191] = __expf(L[8191]) * si;
#pragma unroll
    for (int k = 0; k < 2; ++k) {
      const int i = 1920 + k * 64 + lane;
      if (i < 2047) {
        const f32x4 v = __builtin_nontemporal_load(L4 + i);
        f32x4 o;
        o[0] = __expf(v[0]) * si; o[1] = __expf(v[1]) * si;
        o[2] = __expf(v[2]) * si; o[3] = __expf(v[3]) * si;
        __builtin_nontemporal_store(o, S4 + i);
      }
    }
  } else {
    // waves 1-3: bulk sweep [0, 1920) immediately, no barrier
    const int t = tid - 64;  // 0..191
#pragma unroll
    for (int k = 0; k < 10; ++k) {
      const int i = k * 192 + t;
      const f32x4 v = __builtin_nontemporal_load(L4 + i);
      f32x4 o;
      o[0] = __expf(v[0]) * si; o[1] = __expf(v[1]) * si;
      o[2] = __expf(v[2]) * si; o[3] = __expf(v[3]) * si;
      __builtin_nontemporal_store(o, S4 + i);
    }
  }
}

// ---------------- pass 3: quantized gather + commitment loss ----------------
__global__ __launch_bounds__(256) void finalize_k(const float* __restrict__ tokf,
                                                  const float* __restrict__ cb,
                                                  const float* __restrict__ xf,
                                                  float* __restrict__ q,
                                                  float* __restrict__ loss) {
  const int row  = blockIdx.x * 4 + (threadIdx.x >> 6);
  const int lane = threadIdx.x & 63;
  const int idx  = (int)tokf[row];
  const f32x4* cr = (const f32x4*)(cb + (size_t)idx * D_);
  const f32x4* xr = (const f32x4*)(xf + (size_t)row * D_);
  f32x4* qr = (f32x4*)(q + (size_t)row * D_);
  float ls = 0.f;
#pragma unroll
  for (int j = 0; j < 2; ++j) {
    const int c = lane + j * 64;
    const f32x4 cv = cr[c];
    const f32x4 xv = __builtin_nontemporal_load(xr + c);
    __builtin_nontemporal_store(cv, qr + c);
    const float dx = cv[0] - xv[0], dy = cv[1] - xv[1], dz = cv[2] - xv[2], dw = cv[3] - xv[3];
    ls += dx * dx + dy * dy + dz * dz + dw * dw;
  }
#pragma unroll
  for (int o = 32; o; o >>= 1) ls += __shfl_xor(ls, o);
  if (lane == 0) atomicAdd(loss, ls * (1.0f / 4194304.0f));
}

extern "C" void kernel_launch(void* const* d_in, const int* in_sizes, int n_in,
                              void* d_out, int out_size, void* d_ws, size_t ws_size,
                              hipStream_t stream) {
  const float* x  = (const float*)d_in[0];  // inputs   [8192][512]
  const float* cb = (const float*)d_in[1];  // codebook [8192][512]
  const float* wl = (const float*)d_in[2];  // W_logits [8192][512]
  const float* bl = (const float*)d_in[3];  // b_logits [8192]
  float* out = (float*)d_out;

  float* qout   = out + OFF_Q;
  float* tokf   = out + OFF_TOK;
  float* loss   = out + OFF_LOSS;
  float* soft   = out + OFF_SOFT;
  float* logits = out + OFF_LOGITS;

  // scratch carved from output regions (each rewritten later in the pipeline):
  unsigned short* Abf = (unsigned short*)(out + STAGE_F);  // in soft region
  unsigned short* Wbf = Abf + (size_t)BT_ * D_;
  float* pmaxT = qout;            // [32][8192] in quantized region (finalize overwrites last)
  float* psumT = qout + 262144;   // [32][8192]

  hipMemsetAsync(loss, 0, 4, stream);

  to_bf16_k<<<2048, 256, 0, stream>>>((const f32x4*)x, (const f32x4*)wl,
                                      (u16x4*)Abf, (u16x4*)Wbf);
  gemm8<<<1024, 512, 0, stream>>>(Abf, Wbf, bl, logits, pmaxT, psumT);
  row_finish<<<8192, 256, 0, stream>>>(logits, pmaxT, psumT, x, wl, bl, tokf, soft);
  finalize_k<<<2048, 256, 0, stream>>>(tokf, cb, x, qout, loss);
}